// Round 3
// baseline (238.828 us; speedup 1.0000x reference)
//
#include <hip/hip_runtime.h>

typedef __attribute__((ext_vector_type(8))) __bf16 bf16x8;
typedef __attribute__((ext_vector_type(4))) float f32x4;

constexpr int Bsz   = 128;
constexpr int EE    = 200;
constexpr int EP    = 256;   // padded embed dim
constexpr int KP    = 224;   // padded K loop bound for gemm2/3 (covers 200)
constexpr int NMASK = 192;
constexpr int PE    = 768;
constexpr int M1    = Bsz * 64;     // 8192 visible rows
constexpr long IMG_ELEMS = (long)Bsz * 3 * 256 * 256;

constexpr int VROWS = 16;           // rows per visible mega-block
constexpr int VBLK  = M1 / VROWS;   // 512 visible blocks -> 2 blocks/CU
constexpr int FBLK  = NMASK * 4;    // 768 fold blocks (patch x 32-batch group)
constexpr int ASTR  = 776;          // As LDS stride (768+8): bank-stride 4 mod 32
constexpr int TSTR  = 264;          // vis/full tile LDS stride (256+8)

__device__ __forceinline__ f32x4 mfma16(bf16x8 a, bf16x8 b, f32x4 c) {
    return __builtin_amdgcn_mfma_f32_16x16x32_bf16(a, b, c, 0, 0, 0);
}

// ---------------------------------------------------------------------------
// Prep: pad/convert weights to bf16 (B matrices n-major [n][k]), pad
// pos/biases, emit masked_idx, AND compute dec_masked rows in f32
// (192 blocks, scalar dot: row = mask_token+pos[n], dec = row.W_dec + b_dec).
// No intra-kernel dependencies: reads only raw inputs.
// ---------------------------------------------------------------------------
__global__ __launch_bounds__(256) void k_prep(
    const float* __restrict__ pos, const float* __restrict__ wflat,
    const float* __restrict__ Wenc, const float* __restrict__ Wdec,
    const float* __restrict__ conv_b, const float* __restrict__ b_enc,
    const float* __restrict__ b_dec, const float* __restrict__ mask_token,
    const int* __restrict__ perm,
    float* __restrict__ posP, __bf16* __restrict__ W1t,
    __bf16* __restrict__ W2t, __bf16* __restrict__ W3t,
    float* __restrict__ cbp, float* __restrict__ bep,
    float* __restrict__ dec_masked, float* __restrict__ out_idx)
{
    __shared__ float rowv[256];
    int blk = blockIdx.x, t = threadIdx.x;
    if (blk < 256) {                       // posP [256][256]
        posP[blk * 256 + t] = (t < EE) ? pos[blk * EE + t] : 0.f;
        return;
    }
    blk -= 256;
    if (blk < 768) {                       // W1t [256][768] = wflat padded (n-major)
        int e = blk / 3, k = (blk % 3) * 256 + t;
        W1t[e * 768 + k] = (e < EE) ? (__bf16)wflat[e * 768 + k] : (__bf16)0.f;
        return;
    }
    blk -= 768;
    if (blk < 256) {                       // W2t [256][224] = Wenc^T padded
        if (t < KP) W2t[blk * KP + t] =
            (blk < EE && t < EE) ? (__bf16)Wenc[t * EE + blk] : (__bf16)0.f;
        return;
    }
    blk -= 256;
    if (blk < 768) {                       // W3t [768][224] = Wdec^T padded
        if (t < KP) W3t[blk * KP + t] =
            (t < EE) ? (__bf16)Wdec[t * PE + blk] : (__bf16)0.f;
        return;
    }
    blk -= 768;
    if (blk < NMASK) {                     // masked decoder rows, f32 exact
        const int i = blk;
        const int n = perm[i];
        rowv[t] = (t < EE) ? (mask_token[t] + pos[n * EE + t]) : 0.f;
        __syncthreads();
        float a0 = b_dec[t], a1 = b_dec[t + 256], a2 = b_dec[t + 512];
        #pragma unroll 4
        for (int k = 0; k < EE; ++k) {
            const float rv = rowv[k];
            a0 = fmaf(rv, Wdec[k * PE + t], a0);
            a1 = fmaf(rv, Wdec[k * PE + t + 256], a1);
            a2 = fmaf(rv, Wdec[k * PE + t + 512], a2);
        }
        dec_masked[i * PE + t]       = a0;
        dec_masked[i * PE + t + 256] = a1;
        dec_masked[i * PE + t + 512] = a2;
        return;
    }
    // final block: padded biases + masked_idx output
    cbp[t] = (t < EE) ? conv_b[t] : 0.f;
    bep[t] = (t < EE) ? b_enc[t] : 0.f;
    if (t < NMASK) out_idx[t] = (float)perm[t];
}

// ---------------------------------------------------------------------------
// Mega kernel:
//   blocks [0, 512):    visible 16-row m-tiles, GEMM1->GEMM2->GEMM3 chained
//                       through LDS (B read straight from L2-resident global,
//                       barrier-free K-loops, 4 barriers total).
//   blocks [512, 1280): fold blocks — broadcast masked decoder rows (from
//                       prep's dec_masked) to all batches. Pure writes that
//                       overlap the compute blocks on the same CUs.
// LDS = 16*776*2 = 24832 B; __launch_bounds__(512,4) targets 2 blocks/CU.
// ---------------------------------------------------------------------------
__global__ __launch_bounds__(512, 4) void k_mega(
    const float* __restrict__ x, const __bf16* __restrict__ W1t,
    const __bf16* __restrict__ W2t, const __bf16* __restrict__ W3t,
    const float* __restrict__ cbp, const float* __restrict__ bep,
    const float* __restrict__ posP, const float* __restrict__ bdec,
    const int* __restrict__ perm, const float* __restrict__ dec_masked,
    float* __restrict__ img)
{
    __shared__ __bf16 smem[VROWS * ASTR];  // 24832 B
    __bf16* As    = smem;                  // stride ASTR (phase 0/1)
    __bf16* vis_t = smem;                  // stride TSTR, elems [0, 4224)
    __bf16* ful_t = smem + VROWS * TSTR;   // stride TSTR, elems [4224, 8448)
    __shared__ int nidx[VROWS];

    const int t    = threadIdx.x;
    const int bid  = blockIdx.x;
    const int lane = t & 63, wid = t >> 6;        // 8 waves
    const int quad = lane >> 4, lid = lane & 15;

    if (bid >= VBLK) {
        // ---------------- fold path: broadcast masked rows to 32 batches ----
        const int fb  = bid - VBLK;
        const int i   = fb % NMASK;        // masked patch slot
        const int grp = fb / NMASK;        // 0..3 -> batches [grp*32, grp*32+32)
        const int n   = perm[i];
        if (t < 384) {
            const int sub = t / 192, f4 = t % 192;
            float4 v = *(const float4*)&dec_masked[i * PE + f4 * 4];
            const int p = f4 * 4;
            const int c = p >> 8, py = (p >> 4) & 15, px = p & 15;
            const long base = (long)c * 65536 + ((n >> 4) * 16 + py) * 256
                            + (n & 15) * 16 + px;
            const int b0 = grp * 32 + sub * 16;
            #pragma unroll
            for (int bb = 0; bb < 16; ++bb)
                *(float4*)&img[(long)(b0 + bb) * 3 * 65536 + base] = v;
        }
        return;
    }

    // ---------------- visible path ----------------
    const int m0   = bid * VROWS;
    const int bimg = m0 >> 6;              // batch (VROWS divides 64)
    if (t < VROWS) nidx[t] = perm[NMASK + (m0 & 63) + t];

    // phase 0: stage A tile (16 x 768) from x, f32 -> bf16, into As
    {
        const int row = t >> 5;            // 16 rows x 32 threads
        const int tt  = t & 31;
        const int m = m0 + row;
        const int n = perm[NMASK + (m & 63)];
        const int abase = bimg * 196608 + (n >> 4) * 4096 + (n & 15) * 16;
        #pragma unroll
        for (int it = 0; it < 3; ++it) {
            int k = tt * 8 + it * 256;
            int c = k >> 8, py = (k >> 4) & 15, px = k & 15;
            const float* ap = x + abase + c * 65536 + py * 256 + px;
            float4 a0 = *(const float4*)ap;
            float4 a1 = *(const float4*)(ap + 4);
            bf16x8 av;
            av[0] = (__bf16)a0.x; av[1] = (__bf16)a0.y; av[2] = (__bf16)a0.z; av[3] = (__bf16)a0.w;
            av[4] = (__bf16)a1.x; av[5] = (__bf16)a1.y; av[6] = (__bf16)a1.z; av[7] = (__bf16)a1.w;
            *(bf16x8*)&As[row * ASTR + k] = av;
        }
    }
    __syncthreads();

    // phase 1: 16x256 = A(16x768) . W1t^T, barrier-free K-loop
    const int e0w = wid * 32;
    f32x4 acc1[2] = {};
    for (int k0 = 0; k0 < 768; k0 += 32) {
        bf16x8 a0 = *(const bf16x8*)&As[lid * ASTR + k0 + quad * 8];
        #pragma unroll
        for (int j = 0; j < 2; ++j) {
            bf16x8 bv = *(const bf16x8*)&W1t[(e0w + j * 16 + lid) * 768 + k0 + quad * 8];
            acc1[j] = mfma16(a0, bv, acc1[j]);
        }
    }
    __syncthreads();   // all waves done reading As before vis_t overwrites it

    // epilogue 1: vis_t[m][e] = acc + cb[e] + pos[n][e]  (bf16)
    #pragma unroll
    for (int j = 0; j < 2; ++j) {
        const int e = e0w + j * 16 + lid;
        const float cb = cbp[e];
        #pragma unroll
        for (int r = 0; r < 4; ++r) {
            const int ml = quad * 4 + r;
            vis_t[ml * TSTR + e] = (__bf16)(acc1[j][r] + cb + posP[nidx[ml] * 256 + e]);
        }
    }
    __syncthreads();

    // phase 2: 16x256 = vis(16x224) . W2t^T, barrier-free K-loop
    f32x4 acc2[2] = {};
    for (int k0 = 0; k0 < KP; k0 += 32) {
        bf16x8 a0 = *(const bf16x8*)&vis_t[lid * TSTR + k0 + quad * 8];
        #pragma unroll
        for (int j = 0; j < 2; ++j) {
            bf16x8 bv = *(const bf16x8*)&W2t[(e0w + j * 16 + lid) * KP + k0 + quad * 8];
            acc2[j] = mfma16(a0, bv, acc2[j]);
        }
    }
    // epilogue 2: ful_t disjoint from vis_t, so write needs no barrier first
    #pragma unroll
    for (int j = 0; j < 2; ++j) {
        const int e = e0w + j * 16 + lid;
        const float be = bep[e];
        #pragma unroll
        for (int r = 0; r < 4; ++r) {
            const int ml = quad * 4 + r;
            ful_t[ml * TSTR + e] = (__bf16)(acc2[j][r] + be + posP[nidx[ml] * 256 + e]);
        }
    }
    __syncthreads();

    // phase 3: 16x768 = ful(16x224) . W3t^T, barrier-free K-loop; store to img
    f32x4 acc3[6] = {};
    const int p0w = wid * 96;
    for (int k0 = 0; k0 < KP; k0 += 32) {
        bf16x8 a0 = *(const bf16x8*)&ful_t[lid * TSTR + k0 + quad * 8];
        #pragma unroll
        for (int j = 0; j < 6; ++j) {
            bf16x8 bv = *(const bf16x8*)&W3t[(p0w + j * 16 + lid) * KP + k0 + quad * 8];
            acc3[j] = mfma16(a0, bv, acc3[j]);
        }
    }
    #pragma unroll
    for (int j = 0; j < 6; ++j) {
        const int p = p0w + j * 16 + lid;
        const int c = p >> 8, py = (p >> 4) & 15, px = p & 15;
        const float bd = bdec[p];
        const long obase = (long)(bimg * 3 + c) * 65536 + py * 256 + px;
        #pragma unroll
        for (int r = 0; r < 4; ++r) {
            const int n = nidx[quad * 4 + r];
            img[obase + (n >> 4) * 4096 + (n & 15) * 16] = acc3[j][r] + bd;
        }
    }
}

// ---------------------------------------------------------------------------
extern "C" void kernel_launch(void* const* d_in, const int* in_sizes, int n_in,
                              void* d_out, int out_size, void* d_ws, size_t ws_size,
                              hipStream_t stream)
{
    const float* x          = (const float*)d_in[0];
    const float* conv_w     = (const float*)d_in[1];
    const float* conv_b     = (const float*)d_in[2];
    const float* pos        = (const float*)d_in[3];
    const float* mask_token = (const float*)d_in[4];
    const float* W_enc      = (const float*)d_in[5];
    const float* b_enc      = (const float*)d_in[6];
    const float* W_dec      = (const float*)d_in[7];
    const float* b_dec      = (const float*)d_in[8];
    const int*   perm       = (const int*)d_in[9];
    float* out = (float*)d_out;

    // workspace carve-up (layout kept from verified baseline; first two
    // regions now unused but preserved so offsets stay 16B-aligned)
    __bf16* visible = (__bf16*)d_ws;                    // (unused)
    __bf16* full    = visible + M1 * EP;                // (unused)
    __bf16* W1t     = full + (M1 + NMASK) * EP;         // 256*768
    __bf16* W2t     = W1t + 256 * 768;                  // 256*224
    __bf16* W3t     = W2t + 256 * KP;                   // 768*224
    float*  posP    = (float*)(W3t + 768 * KP);         // 256*256
    float*  cbp     = posP + 256 * 256;                 // 256
    float*  bep     = cbp + 256;                        // 256
    float*  decm    = bep + 256;                        // 192*768

    k_prep<<<256 + 768 + 256 + 768 + NMASK + 1, 256, 0, stream>>>(
        pos, conv_w, W_enc, W_dec, conv_b, b_enc, b_dec, mask_token, perm,
        posP, W1t, W2t, W3t, cbp, bep, decm, out + IMG_ELEMS);
    k_mega<<<VBLK + FBLK, 512, 0, stream>>>(
        x, W1t, W2t, W3t, cbp, bep, posP, b_dec, perm, decm, out);
}